// Round 1
// baseline (73.865 us; speedup 1.0000x reference)
//
#include <hip/hip_runtime.h>

// Qatten forward, restructured:
//   M[h,u,s] = sum_e W_key[h,e,u]*W_sel[h,e,s]            (prep, tiny)
//   C[b, 0:260]   = m[b,h,u]  = states . M                (one bf16 MFMA GEMM,
//   C[b, 260:388] = states . Wv1^T                         512x400 weight panel)
//   C[b, 388:392] = states . Wh^T
//   epilogue per row: logits[h,a] = sum_u m[h,u]*x[a,u],  softmax, v, w_head,
//   head_attend, mag/entropy reductions.

typedef unsigned short u16;
typedef float f32x4 __attribute__((ext_vector_type(4)));
typedef unsigned int u32x4 __attribute__((ext_vector_type(4)));

#define NEGV -99999999.0f

__device__ __forceinline__ u16 f2bf(float f) {
  union { float f; unsigned u; } v; v.f = f;
  unsigned r = v.u + 0x7fffu + ((v.u >> 16) & 1u);
  return (u16)(r >> 16);
}
__device__ __forceinline__ float bf2f(u16 u) {
  union { unsigned u; float f; } v; v.u = ((unsigned)u) << 16;
  return v.f;
}

// ---------------- prep: build packed bf16 weight panel Wp[400][512] ---------
// rows 0..259: M[h,u,:] (n = h*65+u); 260..387: Wv1[e,:]; 388..391: Wh[h,:];
// 392..399: zero. Also zero the 5 accumulator floats.
__global__ __launch_bounds__(256) void kprep(
    const float* __restrict__ Wsel, const float* __restrict__ Wkey,
    const float* __restrict__ Wv1, const float* __restrict__ Wh,
    u16* __restrict__ Wp, float* __restrict__ accs) {
  const int n = blockIdx.x;
  const int t = threadIdx.x;
  if (n == 0 && t < 16) accs[t] = 0.f;
  const int s0 = t, s1 = t + 256;
  float v0 = 0.f, v1 = 0.f;
  if (n < 260) {
    const int h = n / 65, u = n - h * 65;
    const float* wk = Wkey + (size_t)h * 128 * 65 + u;
    const float* ws = Wsel + (size_t)h * 128 * 512;
    for (int e = 0; e < 128; ++e) {
      float k = wk[e * 65];
      v0 = fmaf(k, ws[e * 512 + s0], v0);
      v1 = fmaf(k, ws[e * 512 + s1], v1);
    }
  } else if (n < 388) {
    const int e = n - 260;
    v0 = Wv1[e * 512 + s0];
    v1 = Wv1[e * 512 + s1];
  } else if (n < 392) {
    const int h = n - 388;
    v0 = Wh[h * 512 + s0];
    v1 = Wh[h * 512 + s1];
  }
  Wp[n * 512 + s0] = f2bf(v0);
  Wp[n * 512 + s1] = f2bf(v1);
}

// ---------------- main fused GEMM + epilogue --------------------------------
// 512 blocks x 256 threads; block owns 64 b-rows x all 400 cols; K=512, KC=32.
// LDS: Atile [64][32] bf16 (64B rows, slot^=(row>>1)&3 swizzle) @0 (4KB)
//      Btile [400][32] bf16 same swizzle @4096 (25.6KB)
//      Ctile [64][404] bf16 @0 (51.7KB, reuses staging space post-loop)
__global__ __launch_bounds__(256, 2) void kmain(
    const float* __restrict__ states, const float* __restrict__ agent_qs,
    const int* __restrict__ actions, const u16* __restrict__ Wp,
    const float* __restrict__ bv1, const float* __restrict__ Wv2,
    const float* __restrict__ bv2, const float* __restrict__ bh,
    float* __restrict__ out, float* __restrict__ accs) {
  __shared__ __align__(16) unsigned char smem[51712 + 80];
  u16* const Atile = (u16*)smem;
  u16* const Btile = (u16*)(smem + 4096);
  u16* const Ctile = (u16*)smem;
  float* const red = (float*)(smem + 51712);

  const int tid = threadIdx.x;
  const int wid = tid >> 6;
  const int lane = tid & 63;
  const int b0 = blockIdx.x * 64;

  const f32x4 zf = {0.f, 0.f, 0.f, 0.f};
  f32x4 acc[4][7];
#pragma unroll
  for (int r = 0; r < 4; ++r)
#pragma unroll
    for (int i = 0; i < 7; ++i) acc[r][i] = zf;

  // staging addressing
  const int ar = tid >> 2;  // A row 0..63
  const int ac = tid & 3;   // A 16B chunk 0..3
  const float* aG = states + (size_t)(b0 + ar) * 512 + ac * 8;
  u16* const aW = Atile + ar * 32 + ((ac ^ ((ar >> 1) & 3)) << 3);

  // fragment addressing (same slot formula for A and B reads)
  const int c16 = lane & 15;
  const int sq = lane >> 4;
  const int slot = sq ^ ((c16 >> 1) & 3);

  for (int kt = 0; kt < 16; ++kt) {
    // stage A: fp32 -> bf16
    const float* ag = aG + kt * 32;
    float4 x0 = *(const float4*)(ag);
    float4 x1 = *(const float4*)(ag + 4);
    u32x4 aw;
    aw[0] = (unsigned)f2bf(x0.x) | ((unsigned)f2bf(x0.y) << 16);
    aw[1] = (unsigned)f2bf(x0.z) | ((unsigned)f2bf(x0.w) << 16);
    aw[2] = (unsigned)f2bf(x1.x) | ((unsigned)f2bf(x1.y) << 16);
    aw[3] = (unsigned)f2bf(x1.z) | ((unsigned)f2bf(x1.w) << 16);
    *(u32x4*)aW = aw;
    // stage B: 1600 x 16B chunks
#pragma unroll
    for (int i = 0; i < 7; ++i) {
      int id = tid + (i << 8);
      if (id < 1600) {
        int rw = id >> 2, c = id & 3;
        u32x4 d = *(const u32x4*)(Wp + rw * 512 + kt * 32 + c * 8);
        *(u32x4*)(Btile + rw * 32 + ((c ^ ((rw >> 1) & 3)) << 3)) = d;
      }
    }
    __syncthreads();
    // fragments + MFMA: wave w owns col-frags f = w, w+4, ... (<25)
    u32x4 af[4];
#pragma unroll
    for (int r = 0; r < 4; ++r) {
      int row = (r << 4) + c16;
      af[r] = *(const u32x4*)(Atile + row * 32 + (slot << 3));
    }
#pragma unroll
    for (int i = 0; i < 7; ++i) {
      int f = wid + (i << 2);
      if (f < 25) {
        int col = (f << 4) + c16;
        u32x4 bfr = *(const u32x4*)(Btile + col * 32 + (slot << 3));
#pragma unroll
        for (int r = 0; r < 4; ++r)
          asm("v_mfma_f32_16x16x32_bf16 %0, %1, %2, %0"
              : "+v"(acc[r][i]) : "v"(af[r]), "v"(bfr));
      }
    }
    __syncthreads();
  }

  // MFMA D -> VALU read hazard cover (inline asm bypasses hazard recognizer)
  asm volatile("s_nop 7\n\ts_nop 7" :::);

  // spill acc to Ctile (bf16), overwriting staging space
#pragma unroll
  for (int r = 0; r < 4; ++r)
#pragma unroll
    for (int i = 0; i < 7; ++i) {
      int f = wid + (i << 2);
      if (f < 25) {
        int col = (f << 4) + c16;
        int rowb = (r << 4) + (sq << 2);
#pragma unroll
        for (int j = 0; j < 4; ++j)
          Ctile[(rowb + j) * 404 + col] = f2bf(acc[r][i][j]);
      }
    }
  __syncthreads();

  // ---------------- epilogue: lane group of 4 (sq) per row --------------
  const int rloc = (wid << 4) + c16;  // 0..63
  const int b = b0 + rloc;
  const int qt = sq;  // quarter: u-chunk / e-chunk / duplicate softmax
  const u16* crow = Ctile + rloc * 404;
  const float* srow = states + (size_t)b * 512;

  float m[4][16];
#pragma unroll
  for (int h = 0; h < 4; ++h)
#pragma unroll
    for (int t2 = 0; t2 < 16; ++t2)
      m[h][t2] = bf2f(crow[h * 65 + qt * 16 + t2]);

  float lp[4][8];
#pragma unroll
  for (int h = 0; h < 4; ++h)
#pragma unroll
    for (int a = 0; a < 8; ++a) lp[h][a] = 0.f;

#pragma unroll
  for (int a = 0; a < 8; ++a) {
    const float* xp = srow + a * 64 + qt * 16;
    float4 v0 = *(const float4*)(xp);
    float4 v1 = *(const float4*)(xp + 4);
    float4 v2 = *(const float4*)(xp + 8);
    float4 v3 = *(const float4*)(xp + 12);
    float xv[16] = {v0.x, v0.y, v0.z, v0.w, v1.x, v1.y, v1.z, v1.w,
                    v2.x, v2.y, v2.z, v2.w, v3.x, v3.y, v3.z, v3.w};
#pragma unroll
    for (int h = 0; h < 4; ++h) {
      float s = 0.f;
#pragma unroll
      for (int t2 = 0; t2 < 16; ++t2) s = fmaf(m[h][t2], xv[t2], s);
      lp[h][a] += s;
    }
  }
  // reduce partial logits across the 4-lane group
#pragma unroll
  for (int h = 0; h < 4; ++h)
#pragma unroll
    for (int a = 0; a < 8; ++a) {
      float v = lp[h][a];
      v += __shfl_xor(v, 16, 64);
      v += __shfl_xor(v, 32, 64);
      lp[h][a] = v;
    }
  // u=64 term (agent_qs)
  float4 q0 = *(const float4*)(agent_qs + (size_t)b * 8);
  float4 q1 = *(const float4*)(agent_qs + (size_t)b * 8 + 4);
  float qv[8] = {q0.x, q0.y, q0.z, q0.w, q1.x, q1.y, q1.z, q1.w};
#pragma unroll
  for (int h = 0; h < 4; ++h) {
    float m64 = bf2f(crow[h * 65 + 64]);
#pragma unroll
    for (int a = 0; a < 8; ++a) lp[h][a] = fmaf(m64, qv[a], lp[h][a]);
  }
  // mag partial (count each row once: qt==0)
  float magp = 0.f;
  if (qt == 0) {
#pragma unroll
    for (int h = 0; h < 4; ++h)
#pragma unroll
      for (int a = 0; a < 8; ++a) magp = fmaf(lp[h][a], lp[h][a], magp);
  }
  // v partial: e-chunk per lane
  float vp = 0.f;
#pragma unroll
  for (int e2 = 0; e2 < 32; ++e2) {
    int e = (qt << 5) + e2;
    float c = bf2f(crow[260 + e]) + bv1[e];
    c = fmaxf(c, 0.f);
    vp = fmaf(c, Wv2[e], vp);
  }
  vp += __shfl_xor(vp, 16, 64);
  vp += __shfl_xor(vp, 32, 64);

  // dead mask
  int av[8];
  const int* ap = actions + (size_t)b * 8;
#pragma unroll
  for (int a = 0; a < 8; ++a) av[a] = ap[a];

  const float scale = 0.088388347648318447f;  // 1/sqrt(128)
  float att[8];
#pragma unroll
  for (int a = 0; a < 8; ++a) att[a] = 0.f;
  float entp[4];
#pragma unroll
  for (int h = 0; h < 4; ++h) {
    float whv = fabsf(bf2f(crow[388 + h]) + bh[h]);
    float sc[8];
#pragma unroll
    for (int a = 0; a < 8; ++a)
      sc[a] = (av[a] == 0) ? NEGV : lp[h][a] * scale;
    float mx = sc[0];
#pragma unroll
    for (int a = 1; a < 8; ++a) mx = fmaxf(mx, sc[a]);
    float ex[8];
    float sum = 0.f;
#pragma unroll
    for (int a = 0; a < 8; ++a) { ex[a] = __expf(sc[a] - mx); sum += ex[a]; }
    float inv = 1.f / sum;
    float ent = 0.f;
#pragma unroll
    for (int a = 0; a < 8; ++a) {
      float w = ex[a] * inv;
      att[a] = fmaf(w, whv, att[a]);
      ent = fmaf(w, __logf(w + 1e-8f), ent);
    }
    entp[h] = ent;
  }

  if (qt == 0) {
    float4 o0 = {att[0], att[1], att[2], att[3]};
    float4 o1 = {att[4], att[5], att[6], att[7]};
    *(float4*)(out + (size_t)b * 8) = o0;
    *(float4*)(out + (size_t)b * 8 + 4) = o1;
    out[32768 * 8 + b] = vp + bv2[0];
  }

  // block reduction for mag + entropies, one atomic per value per block
  float r0 = magp;
  float r1 = (qt == 0) ? entp[0] : 0.f;
  float r2 = (qt == 0) ? entp[1] : 0.f;
  float r3 = (qt == 0) ? entp[2] : 0.f;
  float r4 = (qt == 0) ? entp[3] : 0.f;
#pragma unroll
  for (int off = 1; off < 64; off <<= 1) {
    r0 += __shfl_xor(r0, off, 64);
    r1 += __shfl_xor(r1, off, 64);
    r2 += __shfl_xor(r2, off, 64);
    r3 += __shfl_xor(r3, off, 64);
    r4 += __shfl_xor(r4, off, 64);
  }
  if (lane == 0) {
    red[wid * 5 + 0] = r0; red[wid * 5 + 1] = r1; red[wid * 5 + 2] = r2;
    red[wid * 5 + 3] = r3; red[wid * 5 + 4] = r4;
  }
  __syncthreads();
  if (tid < 5) {
    float s = red[tid] + red[5 + tid] + red[10 + tid] + red[15 + tid];
    atomicAdd(&accs[tid], s);
  }
}

// ---------------- finalize scalars ------------------------------------------
__global__ void kfin(const float* __restrict__ accs, float* __restrict__ out) {
  const int t = threadIdx.x;
  if (t == 0) out[294912] = 0.001f * accs[0] * (1.0f / 262144.0f);
  if (t >= 1 && t < 5) out[294912 + t] = -accs[t] * (1.0f / 32768.0f);
}

extern "C" void kernel_launch(void* const* d_in, const int* in_sizes, int n_in,
                              void* d_out, int out_size, void* d_ws, size_t ws_size,
                              hipStream_t stream) {
  const float* agent_qs = (const float*)d_in[0];
  const float* states   = (const float*)d_in[1];
  const int*   actions  = (const int*)d_in[2];
  const float* Wsel = (const float*)d_in[3];
  const float* Wkey = (const float*)d_in[4];
  const float* Wv1  = (const float*)d_in[5];
  const float* bv1  = (const float*)d_in[6];
  const float* Wv2  = (const float*)d_in[7];
  const float* bv2  = (const float*)d_in[8];
  const float* Wh   = (const float*)d_in[9];
  const float* bh   = (const float*)d_in[10];
  float* out = (float*)d_out;
  float* accs = (float*)d_ws;                    // 5 floats used
  u16* Wp = (u16*)((char*)d_ws + 64);            // 400*512 bf16 = 400 KB

  hipLaunchKernelGGL(kprep, dim3(400), dim3(256), 0, stream,
                     Wsel, Wkey, Wv1, Wh, Wp, accs);
  hipLaunchKernelGGL(kmain, dim3(512), dim3(256), 0, stream,
                     states, agent_qs, actions, Wp, bv1, Wv2, bv2, bh, out, accs);
  hipLaunchKernelGGL(kfin, dim3(1), dim3(64), 0, stream, accs, out);
}

// Round 3
// 59.691 us; speedup vs baseline: 1.2374x; 1.2374x over previous
//
#include <hip/hip_runtime.h>

// Qatten forward:
//   M[h,u,s] = sum_e W_key[h,e,u]*W_sel[h,e,s]        (kprep, tiny)
//   panel row p (400 rows, bf16, pre-swizzled + K-tile-blocked in Wp):
//     p = h*64+u (u<64): M[h,u,:];  256+h: M[h,64,:];  264+e: Wv1[e,:];
//     392+h: Wh[h,:];  260-263,396-399: zero
//   kmain: C = states x panel^T via 16x16x32 bf16 MFMA, double-buffered with
//          global_load_lds B staging, __syncthreads drain per tile (robust);
//          fused per-row epilogue.

typedef unsigned short u16;
typedef unsigned int u32;
typedef float f32x4 __attribute__((ext_vector_type(4)));
typedef unsigned int u32x4 __attribute__((ext_vector_type(4)));
typedef unsigned int u32x2 __attribute__((ext_vector_type(2)));
typedef __attribute__((address_space(1))) const u32 gu32;
typedef __attribute__((address_space(3))) u32 lu32;

#define NEGV -99999999.0f

__device__ __forceinline__ u16 f2bf(float f) {
  union { float f; u32 u; } v; v.f = f;
  u32 r = v.u + 0x7fffu + ((v.u >> 16) & 1u);
  return (u16)(r >> 16);
}
__device__ __forceinline__ float bfl(u32 w) { union { u32 u; float f; } v; v.u = w << 16; return v.f; }
__device__ __forceinline__ float bfh(u32 w) { union { u32 u; float f; } v; v.u = w & 0xffff0000u; return v.f; }

// ---------------- prep: packed, K-blocked, swizzled panel --------------------
// Wp layout: 16 K-tiles of 400 rows x 32 bf16; within a tile, row p's 4 16B
// chunks are XOR-swizzled: chunk c lands at slot c ^ ((p>>1)&3). This is the
// exact LDS image global_load_lds reproduces linearly (linear dest +
// pre-swizzled source, per rule 21).
__global__ __launch_bounds__(256) void kprep(
    const float* __restrict__ Wsel, const float* __restrict__ Wkey,
    const float* __restrict__ Wv1, const float* __restrict__ Wh,
    u16* __restrict__ Wp, float* __restrict__ accs) {
  const int p = blockIdx.x;   // 0..399
  const int t = threadIdx.x;
  if (p == 0 && t < 16) accs[t] = 0.f;
#pragma unroll
  for (int half = 0; half < 2; ++half) {
    const int s = t + half * 256;
    float v = 0.f;
    if (p < 260) {
      int h, u;
      if (p < 256) { h = p >> 6; u = p & 63; } else { h = p - 256; u = 64; }
      const float* wk = Wkey + (size_t)h * 128 * 65 + u;
      const float* ws = Wsel + (size_t)h * 128 * 512 + s;
#pragma unroll 4
      for (int e = 0; e < 128; ++e) v = fmaf(wk[e * 65], ws[e * 512], v);
    } else if (p >= 264 && p < 392) {
      v = Wv1[(p - 264) * 512 + s];
    } else if (p >= 392 && p < 396) {
      v = Wh[(p - 392) * 512 + s];
    }
    const int kt = s >> 5, c = (s >> 3) & 3, j = s & 7;
    Wp[kt * 12800 + p * 32 + ((c ^ ((p >> 1) & 3)) << 3) + j] = f2bf(v);
  }
}

// ---------------- main fused GEMM + epilogue --------------------------------
__device__ __forceinline__ void stageA(unsigned char* dst, const float4& x0, const float4& x1) {
  u32x4 aw;
  aw[0] = (u32)f2bf(x0.x) | ((u32)f2bf(x0.y) << 16);
  aw[1] = (u32)f2bf(x0.z) | ((u32)f2bf(x0.w) << 16);
  aw[2] = (u32)f2bf(x1.x) | ((u32)f2bf(x1.y) << 16);
  aw[3] = (u32)f2bf(x1.z) | ((u32)f2bf(x1.w) << 16);
  *(u32x4*)dst = aw;
}

__device__ __forceinline__ void stageB(unsigned char* ldsB, const char* gB, int wid) {
#pragma unroll
  for (int i = 0; i < 7; ++i) {
    const int c = wid + (i << 2);
    if (c < 25)
      __builtin_amdgcn_global_load_lds((gu32*)(gB + c * 1024),
                                       (lu32*)(ldsB + c * 1024), 16, 0, 0);
  }
}

__device__ __forceinline__ void computeT(const unsigned char* buf, int wid, int c16,
                                         int slot, f32x4 acc[4][7]) {
  u32x4 af[4];
#pragma unroll
  for (int r = 0; r < 4; ++r)
    af[r] = *(const u32x4*)(buf + (r * 16 + c16) * 64 + slot * 16);
#pragma unroll
  for (int i = 0; i < 7; ++i) {
    const int f = wid + (i << 2);
    if (f < 25) {
      u32x4 bfr = *(const u32x4*)(buf + 4096 + (f * 16 + c16) * 64 + slot * 16);
#pragma unroll
      for (int r = 0; r < 4; ++r)
        asm("v_mfma_f32_16x16x32_bf16 %0, %1, %2, %0"
            : "+v"(acc[r][i]) : "v"(af[r]), "v"(bfr));
    }
  }
}

__global__ __launch_bounds__(256, 2) void kmain(
    const float* __restrict__ states, const float* __restrict__ agent_qs,
    const int* __restrict__ actions, const u16* __restrict__ Wp,
    const float* __restrict__ bv1, const float* __restrict__ Wv2,
    const float* __restrict__ bv2, const float* __restrict__ bh,
    float* __restrict__ out, float* __restrict__ accs) {
  // buf k at k*29696: A [64 rows][64B] (4096) + B [400 rows][64B] (25600)
  // Ctile [64][416] u16 = 53248B reuses buf space post-loop; red at 59392.
  __shared__ __align__(16) unsigned char smem[59472];
  unsigned char* const buf0 = smem;
  unsigned char* const buf1 = smem + 29696;
  u16* const Ctile = (u16*)smem;
  float* const red = (float*)(smem + 59392);

  const int tid = threadIdx.x;
  const int wid = tid >> 6;
  const int lane = tid & 63;
  const int b0 = blockIdx.x * 64;

  const f32x4 zf = {0.f, 0.f, 0.f, 0.f};
  f32x4 acc[4][7];
#pragma unroll
  for (int r = 0; r < 4; ++r)
#pragma unroll
    for (int i = 0; i < 7; ++i) acc[r][i] = zf;

  const int ar = tid >> 2, ac = tid & 3;
  const float* aG = states + (size_t)(b0 + ar) * 512 + ac * 8;
  const int aWoff = ar * 64 + ((ac ^ ((ar >> 1) & 3)) << 4);

  const int c16 = lane & 15, sq = lane >> 4;
  const int slot = sq ^ ((c16 >> 1) & 3);
  const char* const wpB = (const char*)Wp + lane * 16;

  // ---- prologue: stage tile0 into buf0, prefetch A(1) into regs ----
  float4 ax = *(const float4*)(aG);
  float4 ay = *(const float4*)(aG + 4);
  stageA(buf0 + aWoff, ax, ay);
  stageB(buf0 + 4096, wpB, wid);
  ax = *(const float4*)(aG + 32);
  ay = *(const float4*)(aG + 36);
  __syncthreads();

  // ---- double-buffered K loop: stage(kt+1) || compute(kt), drain, barrier --
  for (int kt = 0; kt < 14; ++kt) {
    unsigned char* const sb = (kt & 1) ? buf0 : buf1;  // stage target
    unsigned char* const cb = (kt & 1) ? buf1 : buf0;  // compute source
    stageA(sb + aWoff, ax, ay);
    stageB(sb + 4096, wpB + (size_t)(kt + 1) * 25600, wid);
    ax = *(const float4*)(aG + (kt + 2) * 32);
    ay = *(const float4*)(aG + (kt + 2) * 32 + 4);
    computeT(cb, wid, c16, slot, acc);
    __syncthreads();
  }
  // kt = 14: stage tile15 (no further A prefetch), compute tile14
  stageA(buf1 + aWoff, ax, ay);
  stageB(buf1 + 4096, wpB + (size_t)15 * 25600, wid);
  computeT(buf0, wid, c16, slot, acc);
  __syncthreads();
  // kt = 15
  computeT(buf1, wid, c16, slot, acc);
  __syncthreads();

  // MFMA D -> VALU read hazard cover (inline asm bypasses hazard recognizer)
  asm volatile("s_nop 7\n\ts_nop 7" :::);

  // spill acc to Ctile (bf16), overwriting staging space
#pragma unroll
  for (int r = 0; r < 4; ++r)
#pragma unroll
    for (int i = 0; i < 7; ++i) {
      const int f = wid + (i << 2);
      if (f < 25) {
        const int col = (f << 4) + c16;
        const int rowb = (r << 4) + (sq << 2);
#pragma unroll
        for (int j = 0; j < 4; ++j)
          Ctile[(rowb + j) * 416 + col] = f2bf(acc[r][i][j]);
      }
    }
  __syncthreads();

  // ---------------- epilogue: 4-lane group (sq) per row ----------------
  const int rloc = (wid << 4) + c16;
  const int b = b0 + rloc;
  const int qt = sq;
  const u16* crow = Ctile + rloc * 416;
  const float* srow = states + (size_t)b * 512;

  float m[4][16];
#pragma unroll
  for (int h = 0; h < 4; ++h) {
    u32x4 w0 = *(const u32x4*)(crow + h * 64 + qt * 16);
    u32x4 w1 = *(const u32x4*)(crow + h * 64 + qt * 16 + 8);
#pragma unroll
    for (int k = 0; k < 4; ++k) {
      m[h][2 * k] = bfl(w0[k]);     m[h][2 * k + 1] = bfh(w0[k]);
      m[h][8 + 2 * k] = bfl(w1[k]); m[h][8 + 2 * k + 1] = bfh(w1[k]);
    }
  }

  float lp[4][8];
#pragma unroll
  for (int h = 0; h < 4; ++h)
#pragma unroll
    for (int a = 0; a < 8; ++a) lp[h][a] = 0.f;

#pragma unroll
  for (int a = 0; a < 8; ++a) {
    const float* xp = srow + a * 64 + qt * 16;
    float4 v0 = *(const float4*)(xp);
    float4 v1 = *(const float4*)(xp + 4);
    float4 v2 = *(const float4*)(xp + 8);
    float4 v3 = *(const float4*)(xp + 12);
    float xv[16] = {v0.x, v0.y, v0.z, v0.w, v1.x, v1.y, v1.z, v1.w,
                    v2.x, v2.y, v2.z, v2.w, v3.x, v3.y, v3.z, v3.w};
#pragma unroll
    for (int h = 0; h < 4; ++h) {
      float s = 0.f;
#pragma unroll
      for (int t2 = 0; t2 < 16; ++t2) s = fmaf(m[h][t2], xv[t2], s);
      lp[h][a] += s;
    }
  }
#pragma unroll
  for (int h = 0; h < 4; ++h)
#pragma unroll
    for (int a = 0; a < 8; ++a) {
      float v = lp[h][a];
      v += __shfl_xor(v, 16, 64);
      v += __shfl_xor(v, 32, 64);
      lp[h][a] = v;
    }
  // u=64 term (agent_qs)
  float4 q0 = *(const float4*)(agent_qs + (size_t)b * 8);
  float4 q1 = *(const float4*)(agent_qs + (size_t)b * 8 + 4);
  float qv[8] = {q0.x, q0.y, q0.z, q0.w, q1.x, q1.y, q1.z, q1.w};
  u32x2 w64 = *(const u32x2*)(crow + 256);
  float m64[4] = {bfl(w64[0]), bfh(w64[0]), bfl(w64[1]), bfh(w64[1])};
#pragma unroll
  for (int h = 0; h < 4; ++h)
#pragma unroll
    for (int a = 0; a < 8; ++a) lp[h][a] = fmaf(m64[h], qv[a], lp[h][a]);

  float magp = 0.f;
  if (qt == 0) {
#pragma unroll
    for (int h = 0; h < 4; ++h)
#pragma unroll
      for (int a = 0; a < 8; ++a) magp = fmaf(lp[h][a], lp[h][a], magp);
  }
  // v partial: e-chunk per lane, all loads vectorized
  float bvv[32], wvv[32], cv[32];
#pragma unroll
  for (int g = 0; g < 8; ++g) {
    *(float4*)(bvv + g * 4) = *(const float4*)(bv1 + qt * 32 + g * 4);
    *(float4*)(wvv + g * 4) = *(const float4*)(Wv2 + qt * 32 + g * 4);
  }
#pragma unroll
  for (int g = 0; g < 4; ++g) {
    u32x4 wv = *(const u32x4*)(crow + 264 + qt * 32 + g * 8);
#pragma unroll
    for (int k = 0; k < 4; ++k) {
      cv[g * 8 + 2 * k] = bfl(wv[k]); cv[g * 8 + 2 * k + 1] = bfh(wv[k]);
    }
  }
  float vp = 0.f;
#pragma unroll
  for (int e2 = 0; e2 < 32; ++e2)
    vp = fmaf(fmaxf(cv[e2] + bvv[e2], 0.f), wvv[e2], vp);
  vp += __shfl_xor(vp, 16, 64);
  vp += __shfl_xor(vp, 32, 64);

  int av[8];
  const int* ap = actions + (size_t)b * 8;
#pragma unroll
  for (int a = 0; a < 8; ++a) av[a] = ap[a];

  u32x2 ww = *(const u32x2*)(crow + 392);
  float whr[4] = {bfl(ww[0]), bfh(ww[0]), bfl(ww[1]), bfh(ww[1])};
  float4 bh4 = *(const float4*)(bh);
  float bhv[4] = {bh4.x, bh4.y, bh4.z, bh4.w};

  const float scale = 0.088388347648318447f;  // 1/sqrt(128)
  float att[8];
#pragma unroll
  for (int a = 0; a < 8; ++a) att[a] = 0.f;
  float entp[4];
#pragma unroll
  for (int h = 0; h < 4; ++h) {
    float whv = fabsf(whr[h] + bhv[h]);
    float sc[8];
#pragma unroll
    for (int a = 0; a < 8; ++a)
      sc[a] = (av[a] == 0) ? NEGV : lp[h][a] * scale;
    float mx = sc[0];
#pragma unroll
    for (int a = 1; a < 8; ++a) mx = fmaxf(mx, sc[a]);
    float ex[8];
    float sum = 0.f;
#pragma unroll
    for (int a = 0; a < 8; ++a) { ex[a] = __expf(sc[a] - mx); sum += ex[a]; }
    float inv = 1.f / sum;
    float ent = 0.f;
#pragma unroll
    for (int a = 0; a < 8; ++a) {
      float w = ex[a] * inv;
      att[a] = fmaf(w, whv, att[a]);
      ent = fmaf(w, __logf(w + 1e-8f), ent);
    }
    entp[h] = ent;
  }

  if (qt == 0) {
    float4 o0 = {att[0], att[1], att[2], att[3]};
    float4 o1 = {att[4], att[5], att[6], att[7]};
    *(float4*)(out + (size_t)b * 8) = o0;
    *(float4*)(out + (size_t)b * 8 + 4) = o1;
    out[32768 * 8 + b] = vp + bv2[0];
  }

  float r0 = magp;
  float r1 = (qt == 0) ? entp[0] : 0.f;
  float r2 = (qt == 0) ? entp[1] : 0.f;
  float r3 = (qt == 0) ? entp[2] : 0.f;
  float r4 = (qt == 0) ? entp[3] : 0.f;
#pragma unroll
  for (int off = 1; off < 64; off <<= 1) {
    r0 += __shfl_xor(r0, off, 64);
    r1 += __shfl_xor(r1, off, 64);
    r2 += __shfl_xor(r2, off, 64);
    r3 += __shfl_xor(r3, off, 64);
    r4 += __shfl_xor(r4, off, 64);
  }
  if (lane == 0) {
    red[wid * 5 + 0] = r0; red[wid * 5 + 1] = r1; red[wid * 5 + 2] = r2;
    red[wid * 5 + 3] = r3; red[wid * 5 + 4] = r4;
  }
  __syncthreads();
  if (tid < 5) {
    float s = red[tid] + red[5 + tid] + red[10 + tid] + red[15 + tid];
    atomicAdd(&accs[tid], s);
  }
}

// ---------------- finalize scalars ------------------------------------------
__global__ void kfin(const float* __restrict__ accs, float* __restrict__ out) {
  const int t = threadIdx.x;
  if (t == 0) out[294912] = 0.001f * accs[0] * (1.0f / 262144.0f);
  if (t >= 1 && t < 5) out[294912 + t] = -accs[t] * (1.0f / 32768.0f);
}

extern "C" void kernel_launch(void* const* d_in, const int* in_sizes, int n_in,
                              void* d_out, int out_size, void* d_ws, size_t ws_size,
                              hipStream_t stream) {
  const float* agent_qs = (const float*)d_in[0];
  const float* states   = (const float*)d_in[1];
  const int*   actions  = (const int*)d_in[2];
  const float* Wsel = (const float*)d_in[3];
  const float* Wkey = (const float*)d_in[4];
  const float* Wv1  = (const float*)d_in[5];
  const float* bv1  = (const float*)d_in[6];
  const float* Wv2  = (const float*)d_in[7];
  const float* bv2  = (const float*)d_in[8];
  const float* Wh   = (const float*)d_in[9];
  const float* bh   = (const float*)d_in[10];
  float* out = (float*)d_out;
  float* accs = (float*)d_ws;                    // 16 floats
  u16* Wp = (u16*)((char*)d_ws + 64);            // 16 tiles x 400 x 32 bf16 = 400 KB

  hipLaunchKernelGGL(kprep, dim3(400), dim3(256), 0, stream,
                     Wsel, Wkey, Wv1, Wh, Wp, accs);
  hipLaunchKernelGGL(kmain, dim3(512), dim3(256), 0, stream,
                     states, agent_qs, actions, Wp, bv1, Wv2, bv2, bh, out, accs);
  hipLaunchKernelGGL(kfin, dim3(1), dim3(64), 0, stream, accs, out);
}

// Round 4
// 56.411 us; speedup vs baseline: 1.3094x; 1.0582x over previous
//
#include <hip/hip_runtime.h>

// Qatten forward:
//   M[h,u,s] = sum_e W_key[h,e,u]*W_sel[h,e,s]        (kprep, LDS-tiled)
//   panel row p (400 rows, bf16, pre-swizzled + K-tile-blocked in Wp):
//     p = h*64+u (u<64): M[h,u,:];  256+h: M[h,64,:];  264+e: Wv1[e,:];
//     392+h: Wh[h,:];  260-263,396-399: zero
//   kmain (512 thr, 8 waves): C = states x panel^T via 16x16x32 bf16 MFMA,
//     double-buffered, global_load_lds B staging, __syncthreads drain;
//     fused epilogue (8 lanes/row); last block finalizes scalars.

typedef unsigned short u16;
typedef unsigned int u32;
typedef float f32x4 __attribute__((ext_vector_type(4)));
typedef unsigned int u32x4 __attribute__((ext_vector_type(4)));
typedef unsigned int u32x2 __attribute__((ext_vector_type(2)));
typedef __attribute__((address_space(1))) const u32 gu32;
typedef __attribute__((address_space(3))) u32 lu32;

#define NEGV -99999999.0f
#define CSTRIDE 424   // u16; 212 words = 20 mod 32 -> 8 rows on 8 banks

__device__ __forceinline__ u16 f2bf(float f) {
  union { float f; u32 u; } v; v.f = f;
  u32 r = v.u + 0x7fffu + ((v.u >> 16) & 1u);
  return (u16)(r >> 16);
}
__device__ __forceinline__ float bfl(u32 w) { union { u32 u; float f; } v; v.u = w << 16; return v.f; }
__device__ __forceinline__ float bfh(u32 w) { union { u32 u; float f; } v; v.u = w & 0xffff0000u; return v.f; }

// store one panel element (row p, col s) with K-tile blocking + XOR swizzle
__device__ __forceinline__ void panel_store(u16* Wp, int p, int s, float v) {
  const int kt = s >> 5, c = (s >> 3) & 3, j = s & 7;
  Wp[kt * 12800 + p * 32 + ((c ^ ((p >> 1) & 3)) << 3) + j] = f2bf(v);
}

// ---------------- kprep ------------------------------------------------------
// blocks 0..127: M-part. h = bid>>5, s0 = (bid&31)*16. Stage Wsel[h][:,s0:s0+16]
//   (2048 f32) + Wkey[h] (8320 f32) in LDS; thread t: u=t>>2, 4 s-values.
// blocks 128..135: copy/zero rows 260..399; block 128 zeroes accs.
__global__ __launch_bounds__(256) void kprep(
    const float* __restrict__ Wsel, const float* __restrict__ Wkey,
    const float* __restrict__ Wv1, const float* __restrict__ Wh,
    u16* __restrict__ Wp, float* __restrict__ accs) {
  const int bid = blockIdx.x, t = threadIdx.x;
  if (bid < 128) {
    __shared__ float wsS[2048];   // [e][16]
    __shared__ float wkS[8320];   // [e][65]
    const int h = bid >> 5, s0 = (bid & 31) << 4;
    for (int i = t; i < 2048; i += 256)
      wsS[i] = Wsel[((size_t)h * 128 + (i >> 4)) * 512 + s0 + (i & 15)];
    for (int i = t; i < 8320; i += 256)
      wkS[i] = Wkey[(size_t)h * 8320 + i];
    __syncthreads();
    {
      const int u = t >> 2, sl0 = (t & 3) << 2;
      float a0 = 0.f, a1 = 0.f, a2 = 0.f, a3 = 0.f;
      for (int e = 0; e < 128; ++e) {
        const float k = wkS[e * 65 + u];
        const float* wr = wsS + e * 16 + sl0;
        a0 = fmaf(k, wr[0], a0); a1 = fmaf(k, wr[1], a1);
        a2 = fmaf(k, wr[2], a2); a3 = fmaf(k, wr[3], a3);
      }
      const int p = h * 64 + u, s = s0 + sl0;
      panel_store(Wp, p, s, a0);     panel_store(Wp, p, s + 1, a1);
      panel_store(Wp, p, s + 2, a2); panel_store(Wp, p, s + 3, a3);
    }
    if (t < 16) {  // u = 64 row
      float a = 0.f;
      for (int e = 0; e < 128; ++e)
        a = fmaf(wkS[e * 65 + 64], wsS[e * 16 + t], a);
      panel_store(Wp, 256 + h, s0 + t, a);
    }
  } else {
    if (bid == 128 && t < 16) accs[t] = 0.f;
    for (int row = 260 + (bid - 128); row < 400; row += 8) {
      for (int s = t; s < 512; s += 256) {
        float v = 0.f;
        if (row >= 264 && row < 392) v = Wv1[(row - 264) * 512 + s];
        else if (row >= 392 && row < 396) v = Wh[(row - 392) * 512 + s];
        panel_store(Wp, row, s, v);
      }
    }
  }
}

// ---------------- kmain ------------------------------------------------------
__device__ __forceinline__ void stageB(unsigned char* ldsB, const char* gB, int wid) {
#pragma unroll
  for (int i = 0; i < 4; ++i) {
    const int c = wid + (i << 3);
    if (c < 25)
      __builtin_amdgcn_global_load_lds((gu32*)(gB + c * 1024),
                                       (lu32*)(ldsB + c * 1024), 16, 0, 0);
  }
}

__device__ __forceinline__ void stageA8(unsigned char* dst, const float4& x) {
  u32x2 w;
  w[0] = (u32)f2bf(x.x) | ((u32)f2bf(x.y) << 16);
  w[1] = (u32)f2bf(x.z) | ((u32)f2bf(x.w) << 16);
  *(u32x2*)dst = w;
}

__device__ __forceinline__ void computeT(const unsigned char* buf, int wid, int c16,
                                         int slot, f32x4 acc[4][4]) {
  u32x4 af[4];
#pragma unroll
  for (int r = 0; r < 4; ++r)
    af[r] = *(const u32x4*)(buf + (r * 16 + c16) * 64 + slot * 16);
#pragma unroll
  for (int i = 0; i < 4; ++i) {
    const int f = wid + (i << 3);
    if (f < 25) {
      u32x4 bfr = *(const u32x4*)(buf + 4096 + (f * 16 + c16) * 64 + slot * 16);
#pragma unroll
      for (int r = 0; r < 4; ++r)
        asm("v_mfma_f32_16x16x32_bf16 %0, %1, %2, %0"
            : "+v"(acc[r][i]) : "v"(af[r]), "v"(bfr));
    }
  }
}

__global__ __launch_bounds__(512, 4) void kmain(
    const float* __restrict__ states, const float* __restrict__ agent_qs,
    const int* __restrict__ actions, const u16* __restrict__ Wp,
    const float* __restrict__ bv1, const float* __restrict__ Wv2,
    const float* __restrict__ bv2, const float* __restrict__ bh,
    float* __restrict__ out, float* __restrict__ accs) {
  // buf k at k*29696: A [64 rows][64B] + B [400 rows][64B]
  // Ctile [64][CSTRIDE] u16 = 54272B reuses buf space; red at 59392 (40 f32).
  __shared__ __align__(16) unsigned char smem[59392 + 160];
  unsigned char* const buf0 = smem;
  unsigned char* const buf1 = smem + 29696;
  u16* const Ctile = (u16*)smem;
  float* const red = (float*)(smem + 59392);

  const int tid = threadIdx.x;
  const int wid = tid >> 6;
  const int lane = tid & 63;
  const int b0 = blockIdx.x * 64;

  const f32x4 zf = {0.f, 0.f, 0.f, 0.f};
  f32x4 acc[4][4];
#pragma unroll
  for (int r = 0; r < 4; ++r)
#pragma unroll
    for (int i = 0; i < 4; ++i) acc[r][i] = zf;

  // A staging: 512 threads x 8B. row ar = tid>>3, 8B-chunk ac8 = tid&7.
  const int ar = tid >> 3, ac8 = tid & 7;
  const float* aG = states + (size_t)(b0 + ar) * 512 + ac8 * 4;
  const int aWoff = ar * 64 + (((ac8 >> 1) ^ ((ar >> 1) & 3)) << 4) + (ac8 & 1) * 8;

  const int c16 = lane & 15, sq = lane >> 4;
  const int slot = sq ^ ((c16 >> 1) & 3);
  const char* const wpB = (const char*)Wp + lane * 16;

  // ---- prologue ----
  float4 ax = *(const float4*)(aG);
  stageA8(buf0 + aWoff, ax);
  stageB(buf0 + 4096, wpB, wid);
  ax = *(const float4*)(aG + 32);
  __syncthreads();

  // ---- double-buffered K loop ----
  for (int kt = 0; kt < 15; ++kt) {
    unsigned char* const sb = (kt & 1) ? buf0 : buf1;  // tile kt+1
    unsigned char* const cb = (kt & 1) ? buf1 : buf0;  // tile kt
    stageA8(sb + aWoff, ax);
    stageB(sb + 4096, wpB + (size_t)(kt + 1) * 25600, wid);
    if (kt < 14) ax = *(const float4*)(aG + (kt + 2) * 32);
    computeT(cb, wid, c16, slot, acc);
    __syncthreads();
  }
  computeT(buf1, wid, c16, slot, acc);  // tile 15
  __syncthreads();

  // MFMA D -> VALU hazard cover (inline-asm MFMA bypasses hazard recognizer)
  asm volatile("s_nop 7\n\ts_nop 7" :::);

  // spill acc to Ctile (bf16)
#pragma unroll
  for (int r = 0; r < 4; ++r)
#pragma unroll
    for (int i = 0; i < 4; ++i) {
      const int f = wid + (i << 3);
      if (f < 25) {
        const int col = (f << 4) + c16;
        const int rowb = (r << 4) + (sq << 2);
#pragma unroll
        for (int j = 0; j < 4; ++j)
          Ctile[(rowb + j) * CSTRIDE + col] = f2bf(acc[r][i][j]);
      }
    }
  __syncthreads();

  // ---------------- epilogue: 8-lane group per row ----------------
  const int r = (wid << 3) + (lane >> 3);  // 0..63
  const int q8 = lane & 7;
  const int b = b0 + r;
  const u16* crow = Ctile + r * CSTRIDE;
  const float* srow = states + (size_t)b * 512;

  float m[4][8];
#pragma unroll
  for (int h = 0; h < 4; ++h) {
    u32x4 w = *(const u32x4*)(crow + h * 64 + q8 * 8);
#pragma unroll
    for (int k = 0; k < 4; ++k) {
      m[h][2 * k] = bfl(w[k]); m[h][2 * k + 1] = bfh(w[k]);
    }
  }

  float lp[4][8];
#pragma unroll
  for (int h = 0; h < 4; ++h)
#pragma unroll
    for (int a = 0; a < 8; ++a) lp[h][a] = 0.f;

#pragma unroll
  for (int a = 0; a < 8; ++a) {
    const float* xp = srow + a * 64 + q8 * 8;
    float4 v0 = *(const float4*)(xp);
    float4 v1 = *(const float4*)(xp + 4);
    float xv[8] = {v0.x, v0.y, v0.z, v0.w, v1.x, v1.y, v1.z, v1.w};
#pragma unroll
    for (int h = 0; h < 4; ++h) {
      float s = 0.f;
#pragma unroll
      for (int j = 0; j < 8; ++j) s = fmaf(m[h][j], xv[j], s);
      lp[h][a] = s;
    }
  }
#pragma unroll
  for (int h = 0; h < 4; ++h)
#pragma unroll
    for (int a = 0; a < 8; ++a) {
      float v = lp[h][a];
      v += __shfl_xor(v, 1, 64);
      v += __shfl_xor(v, 2, 64);
      v += __shfl_xor(v, 4, 64);
      lp[h][a] = v;
    }
  // u=64 term (agent_qs)
  float4 q0 = *(const float4*)(agent_qs + (size_t)b * 8);
  float4 q1 = *(const float4*)(agent_qs + (size_t)b * 8 + 4);
  float qv[8] = {q0.x, q0.y, q0.z, q0.w, q1.x, q1.y, q1.z, q1.w};
  u32x2 w64 = *(const u32x2*)(crow + 256);
  float m64[4] = {bfl(w64[0]), bfh(w64[0]), bfl(w64[1]), bfh(w64[1])};
#pragma unroll
  for (int h = 0; h < 4; ++h)
#pragma unroll
    for (int a = 0; a < 8; ++a) lp[h][a] = fmaf(m64[h], qv[a], lp[h][a]);

  float magp = 0.f;
  if (q8 == 0) {
#pragma unroll
    for (int h = 0; h < 4; ++h)
#pragma unroll
      for (int a = 0; a < 8; ++a) magp = fmaf(lp[h][a], lp[h][a], magp);
  }
  // v partial: 16 e per lane
  float bvv[16], wvv[16], cv[16];
#pragma unroll
  for (int g = 0; g < 4; ++g) {
    *(float4*)(bvv + g * 4) = *(const float4*)(bv1 + q8 * 16 + g * 4);
    *(float4*)(wvv + g * 4) = *(const float4*)(Wv2 + q8 * 16 + g * 4);
  }
#pragma unroll
  for (int g = 0; g < 2; ++g) {
    u32x4 wv = *(const u32x4*)(crow + 264 + q8 * 16 + g * 8);
#pragma unroll
    for (int k = 0; k < 4; ++k) {
      cv[g * 8 + 2 * k] = bfl(wv[k]); cv[g * 8 + 2 * k + 1] = bfh(wv[k]);
    }
  }
  float vp = 0.f;
#pragma unroll
  for (int e2 = 0; e2 < 16; ++e2)
    vp = fmaf(fmaxf(cv[e2] + bvv[e2], 0.f), wvv[e2], vp);
  vp += __shfl_xor(vp, 1, 64);
  vp += __shfl_xor(vp, 2, 64);
  vp += __shfl_xor(vp, 4, 64);

  int av[8];
  const int* ap = actions + (size_t)b * 8;
#pragma unroll
  for (int a = 0; a < 8; ++a) av[a] = ap[a];

  u32x2 ww = *(const u32x2*)(crow + 392);
  float whr[4] = {bfl(ww[0]), bfh(ww[0]), bfl(ww[1]), bfh(ww[1])};
  float4 bh4 = *(const float4*)(bh);
  float bhv[4] = {bh4.x, bh4.y, bh4.z, bh4.w};

  const float scale = 0.088388347648318447f;  // 1/sqrt(128)
  float att[8];
#pragma unroll
  for (int a = 0; a < 8; ++a) att[a] = 0.f;
  float entp[4];
#pragma unroll
  for (int h = 0; h < 4; ++h) {
    float whv = fabsf(whr[h] + bhv[h]);
    float sc[8];
#pragma unroll
    for (int a = 0; a < 8; ++a)
      sc[a] = (av[a] == 0) ? NEGV : lp[h][a] * scale;
    float mx = sc[0];
#pragma unroll
    for (int a = 1; a < 8; ++a) mx = fmaxf(mx, sc[a]);
    float ex[8];
    float sum = 0.f;
#pragma unroll
    for (int a = 0; a < 8; ++a) { ex[a] = __expf(sc[a] - mx); sum += ex[a]; }
    float inv = 1.f / sum;
    float ent = 0.f;
#pragma unroll
    for (int a = 0; a < 8; ++a) {
      float w = ex[a] * inv;
      att[a] = fmaf(w, whv, att[a]);
      ent = fmaf(w, __logf(w + 1e-8f), ent);
    }
    entp[h] = ent;
  }

  if (q8 == 0) {
    float4 o0 = {att[0], att[1], att[2], att[3]};
    float4 o1 = {att[4], att[5], att[6], att[7]};
    *(float4*)(out + (size_t)b * 8) = o0;
    *(float4*)(out + (size_t)b * 8 + 4) = o1;
    out[262144 + b] = vp + bv2[0];
  }

  float r0 = magp;
  float r1 = (q8 == 0) ? entp[0] : 0.f;
  float r2 = (q8 == 0) ? entp[1] : 0.f;
  float r3 = (q8 == 0) ? entp[2] : 0.f;
  float r4 = (q8 == 0) ? entp[3] : 0.f;
#pragma unroll
  for (int off = 1; off < 64; off <<= 1) {
    r0 += __shfl_xor(r0, off, 64);
    r1 += __shfl_xor(r1, off, 64);
    r2 += __shfl_xor(r2, off, 64);
    r3 += __shfl_xor(r3, off, 64);
    r4 += __shfl_xor(r4, off, 64);
  }
  if (lane == 0) {
    red[wid * 5 + 0] = r0; red[wid * 5 + 1] = r1; red[wid * 5 + 2] = r2;
    red[wid * 5 + 3] = r3; red[wid * 5 + 4] = r4;
  }
  __syncthreads();
  if (tid < 5) {
    float s = 0.f;
#pragma unroll
    for (int w = 0; w < 8; ++w) s += red[w * 5 + tid];
    atomicAdd(&accs[tid], s);
  }
  __syncthreads();  // block's atomics retired before counting
  if (tid == 0) {
    u32* cnt = (u32*)(accs + 8);
    if (atomicAdd(cnt, 1u) == 511u) {  // last block finalizes
      float a0 = atomicAdd(&accs[0], 0.f);
      float a1 = atomicAdd(&accs[1], 0.f);
      float a2 = atomicAdd(&accs[2], 0.f);
      float a3 = atomicAdd(&accs[3], 0.f);
      float a4 = atomicAdd(&accs[4], 0.f);
      out[294912] = 0.001f * a0 * (1.0f / 262144.0f);
      out[294913] = -a1 * (1.0f / 32768.0f);
      out[294914] = -a2 * (1.0f / 32768.0f);
      out[294915] = -a3 * (1.0f / 32768.0f);
      out[294916] = -a4 * (1.0f / 32768.0f);
    }
  }
}

extern "C" void kernel_launch(void* const* d_in, const int* in_sizes, int n_in,
                              void* d_out, int out_size, void* d_ws, size_t ws_size,
                              hipStream_t stream) {
  const float* agent_qs = (const float*)d_in[0];
  const float* states   = (const float*)d_in[1];
  const int*   actions  = (const int*)d_in[2];
  const float* Wsel = (const float*)d_in[3];
  const float* Wkey = (const float*)d_in[4];
  const float* Wv1  = (const float*)d_in[5];
  const float* bv1  = (const float*)d_in[6];
  const float* Wv2  = (const float*)d_in[7];
  const float* bv2  = (const float*)d_in[8];
  const float* Wh   = (const float*)d_in[9];
  const float* bh   = (const float*)d_in[10];
  float* out = (float*)d_out;
  float* accs = (float*)d_ws;                    // 16 floats (incl. counter)
  u16* Wp = (u16*)((char*)d_ws + 64);            // 16 tiles x 400 x 32 bf16

  hipLaunchKernelGGL(kprep, dim3(136), dim3(256), 0, stream,
                     Wsel, Wkey, Wv1, Wh, Wp, accs);
  hipLaunchKernelGGL(kmain, dim3(512), dim3(512), 0, stream,
                     states, agent_qs, actions, Wp, bv1, Wv2, bv2, bh, out, accs);
}